// Round 7
// baseline (135.325 us; speedup 1.0000x reference)
//
#include <hip/hip_runtime.h>
#include <math.h>

#define T_TOTAL 2048
#define B_TOTAL 4096
#define B2      (B_TOTAL / 2)   // float4 column-pairs per row = 2048
#define PPB     4               // pairs per block
#define NCHUNK  64              // T chunks per block (= threads/PPB)
#define TCHUNK  (T_TOTAL / NCHUNK)   // 32 timesteps per thread

typedef float fvec4 __attribute__((ext_vector_type(4)));

__device__ __forceinline__ int delta_of(float p, float q) {
    // is_push = p>=0.5 && p>=q ; is_pop = q>=0.5 && q>p
    return (p >= 0.5f && p >= q) ? 1 : ((q >= 0.5f && q > p) ? -1 : 0);
}

__device__ __forceinline__ float fast_tanh(float x) {
    // tanh(x) = 1 - 2/(exp2(2x*log2e)+1); exact at 0, saturates to +-1.
    float e = __builtin_amdgcn_exp2f(x * 2.885390081777927f);
    return 1.0f - 2.0f / (e + 1.0f);
}

__device__ __forceinline__ int sext2(unsigned int bits2) {
    return ((int)(bits2 << 30)) >> 30;  // 2-bit signed: 00->0, 01->+1, 11->-1
}

// Fused single kernel: block owns PPB column-pairs x full T.
//  Phase A: each thread computes its 32-step chunk's deltas (packed, registers)
//           + chunk sum -> LDS.
//  __syncthreads()
//  Phase B: exclusive prefix over LDS chunk sums (broadcast reads), decode
//           registers, emit {count, tanh(count)} x2 as 16B stores.
__global__ void __launch_bounds__(256)
scan_fused(const fvec4* __restrict__ x4, fvec4* __restrict__ o4) {
    const int tid = threadIdx.x;
    const int pl  = tid & (PPB - 1);   // pair within block: 0..3
    const int ch  = tid >> 2;          // chunk: 0..63
    const int p   = blockIdx.x * PPB + pl;   // global pair 0..B2-1
    const int t0  = ch * TCHUNK;

    __shared__ int2 sums[NCHUNK * PPB];      // [chunk][pair], 2 KiB

    int s0 = 0, s1 = 0;
    unsigned long long w0 = 0ull, w1 = 0ull;

#pragma unroll
    for (int t = 0; t < 16; ++t) {
        fvec4 v = x4[(size_t)(t0 + t) * B2 + p];
        int d0 = delta_of(v.x, v.y);
        int d1 = delta_of(v.z, v.w);
        s0 += d0; s1 += d1;
        unsigned int nib = (unsigned int)(d0 & 3) | ((unsigned int)(d1 & 3) << 2);
        w0 |= (unsigned long long)nib << (4 * t);
    }
#pragma unroll
    for (int t = 16; t < 32; ++t) {
        fvec4 v = x4[(size_t)(t0 + t) * B2 + p];
        int d0 = delta_of(v.x, v.y);
        int d1 = delta_of(v.z, v.w);
        s0 += d0; s1 += d1;
        unsigned int nib = (unsigned int)(d0 & 3) | ((unsigned int)(d1 & 3) << 2);
        w1 |= (unsigned long long)nib << (4 * (t - 16));
    }

    int2 s; s.x = s0; s.y = s1;
    sums[tid] = s;
    __syncthreads();

    // Exclusive prefix over chunks 0..ch-1 for this pair.
    // All lanes at iteration cc read sums[cc*PPB+pl] -> 4 addresses, broadcast.
    int c0 = 0, c1 = 0;
    for (int cc = 0; cc < ch; ++cc) {
        int2 v = sums[cc * PPB + pl];
        c0 += v.x; c1 += v.y;
    }

#pragma unroll
    for (int t = 0; t < 16; ++t) {
        unsigned int nib = (unsigned int)(w0 >> (4 * t)) & 0xFu;
        c0 += sext2(nib & 3u);
        c1 += sext2(nib >> 2);
        float f0 = (float)c0, f1 = (float)c1;
        fvec4 o; o.x = f0; o.y = fast_tanh(f0); o.z = f1; o.w = fast_tanh(f1);
        o4[(size_t)(t0 + t) * B2 + p] = o;
    }
#pragma unroll
    for (int t = 16; t < 32; ++t) {
        unsigned int nib = (unsigned int)(w1 >> (4 * (t - 16))) & 0xFu;
        c0 += sext2(nib & 3u);
        c1 += sext2(nib >> 2);
        float f0 = (float)c0, f1 = (float)c1;
        fvec4 o; o.x = f0; o.y = fast_tanh(f0); o.z = f1; o.w = fast_tanh(f1);
        o4[(size_t)(t0 + t) * B2 + p] = o;
    }
}

extern "C" void kernel_launch(void* const* d_in, const int* in_sizes, int n_in,
                              void* d_out, int out_size, void* d_ws, size_t ws_size,
                              hipStream_t stream) {
    const fvec4* x4 = (const fvec4*)d_in[0];
    fvec4* o4 = (fvec4*)d_out;
    // 512 blocks x 256 threads = 2 blocks/CU, 8 waves/CU. No workspace needed.
    scan_fused<<<dim3(B2 / PPB), dim3(256), 0, stream>>>(x4, o4);
}